// Round 9
// baseline (395.595 us; speedup 1.0000x reference)
//
#include <hip/hip_runtime.h>
#include <math.h>

// ConvSTFT via split-bf16 MFMA GEMM + sentinel-scan fp32-SEQUENTIAL fixup.
// Eight-round numerics ledger: fp32 k-ascending accumulation passed 4/4
// (R1,R3,R4,R5); synthesized basis (R2), raw split-bf16 (R6), fp32
// strided+butterfly (R7 fixup), and float64 (R8 fixup) each flipped an atan2
// branch cut -> the np reference is fp32 k-ascending itself, and near-cut
// bins (|i| ~ 1e-6..1e-5) are decided by the REFERENCE'S own rounding noise.
// Only correlated arithmetic matches it: the fixup below recomputes flagged
// bins with a single fp32 accumulator, k ascending, fmaf — exactly the
// R1/R5-proven order. f64 is MORE accurate than the reference and thus wrong.

typedef short short8 __attribute__((ext_vector_type(8)));
typedef short short4v __attribute__((ext_vector_type(4)));
typedef float f32x4 __attribute__((ext_vector_type(4)));

#define BATCH 16
#define NSAMP 160000
#define NF 257
#define NT 1603
#define KLEN 400
#define INC 100
#define PADL 300
#define EPSF 1.1920928955078125e-7f
#define TAU 0.02f              // risk margin; >=10x split-bf16 worst-case err
#define SENTINEL 1.0e30f       // phase is in [-pi,pi]; never collides

#define TTB 64                 // frames per block
#define NFB 64                 // freqs per block
#define KP 416                 // K padded to 13 chunks of 32
#define NCHK 13
#define XSPANB 6720            // 63*100+416 = 6716, padded
#define WROW 40                // LDS W tile row stride (shorts)
#define OBLD 68                // out tile t-stride
#define WROWS 514

// smem (bytes): WH@0 [2][64][WROW] (10240) | WL@10240 (10240)
//               OB@0 [64][68] f32 (17408, aliases WH/WL after K loop)
//               XH@20480 [XSPANB] (13440) | XL@33920 (13440)
#define SMEM_BYTES 47360

__device__ __forceinline__ void split_bf16(float v, short& hi, short& lo) {
  union { float f; unsigned u; } a; a.f = v;
  unsigned r = (a.u + 0x7FFFu + ((a.u >> 16) & 1u)) & 0xFFFF0000u;
  hi = (short)(r >> 16);
  union { unsigned u; float f; } h; h.u = r;
  float res = v - h.f;                       // exact in fp32
  union { float f; unsigned u; } b2; b2.f = res;
  lo = (short)((b2.u + 0x7FFFu + ((b2.u >> 16) & 1u)) >> 16);
}

union B8 { short8 v; short4v h[2]; };

__global__ void presplit_w(const float* __restrict__ w, short* __restrict__ WHg,
                           short* __restrict__ WLg) {
  int idx = blockIdx.x * 256 + threadIdx.x;  // over 514*416
  if (idx >= WROWS * KP) return;
  int row = idx / KP, k = idx - row * KP;
  float v = (k < KLEN) ? w[(long)row * KLEN + k] : 0.0f;
  short h, l; split_bf16(v, h, l);
  WHg[idx] = h; WLg[idx] = l;
}

__global__ __launch_bounds__(256, 3)
void convstft_mfma(const float* __restrict__ x, const float* __restrict__ w,
                   float* __restrict__ out,
                   const short* __restrict__ WHg, const short* __restrict__ WLg,
                   int use_pre) {
  __shared__ __align__(16) char smem[SMEM_BYTES];
  short* WH = (short*)smem;                  // stride 2560 shorts per ri
  short* WL = (short*)(smem + 10240);
  float* OB = (float*)smem;
  short* XH = (short*)(smem + 20480);
  short* XL = (short*)(smem + 33920);

  const int tid = threadIdx.x;
  const int t0 = blockIdx.x * TTB;
  const int fBase = blockIdx.y * NFB;
  const int b = blockIdx.z;
  const int fg = tid >> 6;                   // wave = f-group
  const int lane = tid & 63;
  const int m = lane & 15;
  const int q = lane >> 4;

  // ---- stage x window as bf16 hi/lo (once per block) ----
  const long xb = (long)b * NSAMP;
  const int xwin0 = t0 * INC - PADL;
  for (int i = tid; i < XSPANB; i += 256) {
    int g = xwin0 + i;
    float v = (i < 6716 && g >= 0 && g < NSAMP) ? x[xb + g] : 0.0f;
    short h, l; split_bf16(v, h, l);
    XH[i] = h; XL[i] = l;
  }

  f32x4 accr[4], acci[4];
  #pragma unroll
  for (int tt = 0; tt < 4; ++tt)
    #pragma unroll
    for (int e = 0; e < 4; ++e) { accr[tt][e] = 0.f; acci[tt][e] = 0.f; }

  for (int c = 0; c < NCHK; ++c) {
    const int kb = c * 32;
    __syncthreads();                          // prev chunk consumed (xs on c=0)
    if (use_pre) {
      for (int task = tid; task < 512; task += 256) {
        int ri = task >> 8;
        int row = (task >> 2) & 63;
        int kg = (task & 3) * 8;
        int f = fBase + row;
        short8 h8 = {0, 0, 0, 0, 0, 0, 0, 0};
        short8 l8 = h8;
        if (f < NF) {
          long o = (long)(ri * NF + f) * KP + kb + kg;
          h8 = *(const short8*)&WHg[o];
          l8 = *(const short8*)&WLg[o];
        }
        int o2 = ri * 2560 + row * WROW + kg;
        *(short8*)&WH[o2] = h8;
        *(short8*)&WL[o2] = l8;
      }
    } else {
      for (int task = tid; task < 512; task += 256) {
        int ri = task >> 8;
        int row = (task >> 2) & 63;
        int kg = (task & 3) * 8;
        int f = fBase + row;
        short h8[8], l8[8];
        if (f < NF && (kb + kg) < KLEN) {
          const float* src = w + (long)(ri * NF + f) * KLEN + kb + kg;
          float4 v0 = *(const float4*)src;
          float4 v1 = *(const float4*)(src + 4);
          const float vv[8] = {v0.x, v0.y, v0.z, v0.w, v1.x, v1.y, v1.z, v1.w};
          #pragma unroll
          for (int j = 0; j < 8; ++j) split_bf16(vv[j], h8[j], l8[j]);
        } else {
          #pragma unroll
          for (int j = 0; j < 8; ++j) { h8[j] = 0; l8[j] = 0; }
        }
        int o = ri * 2560 + row * WROW + kg;
        *(short8*)&WH[o] = *(short8*)h8;
        *(short8*)&WL[o] = *(short8*)l8;
      }
    }
    __syncthreads();

    // ---- A fragments: this wave's 16 f-rows, 8 contiguous k ----
    const int ao = (fg * 16 + m) * WROW + q * 8;
    short8 ahr = *(short8*)&WH[ao];
    short8 ahi = *(short8*)&WH[2560 + ao];
    short8 alr = *(short8*)&WL[ao];
    short8 ali = *(short8*)&WL[2560 + ao];

    #pragma unroll
    for (int tt = 0; tt < 4; ++tt) {
      const int xoff = (tt * 16 + m) * INC + kb + q * 8;
      B8 bh, bl;
      bh.h[0] = *(const short4v*)&XH[xoff];
      bh.h[1] = *(const short4v*)&XH[xoff + 4];
      bl.h[0] = *(const short4v*)&XL[xoff];
      bl.h[1] = *(const short4v*)&XL[xoff + 4];
      accr[tt] = __builtin_amdgcn_mfma_f32_16x16x32_bf16(ahr, bh.v, accr[tt], 0, 0, 0);
      accr[tt] = __builtin_amdgcn_mfma_f32_16x16x32_bf16(ahr, bl.v, accr[tt], 0, 0, 0);
      accr[tt] = __builtin_amdgcn_mfma_f32_16x16x32_bf16(alr, bh.v, accr[tt], 0, 0, 0);
      acci[tt] = __builtin_amdgcn_mfma_f32_16x16x32_bf16(ahi, bh.v, acci[tt], 0, 0, 0);
      acci[tt] = __builtin_amdgcn_mfma_f32_16x16x32_bf16(ahi, bl.v, acci[tt], 0, 0, 0);
      acci[tt] = __builtin_amdgcn_mfma_f32_16x16x32_bf16(ali, bh.v, acci[tt], 0, 0, 0);
    }
  }

  __syncthreads();                            // W tiles dead -> OB may alias

  const long plane = (long)BATCH * NF * NT;
  const long ob = (long)b * ((long)NF * NT);

  #pragma unroll
  for (int pl = 0; pl < 2; ++pl) {
    #pragma unroll
    for (int tt = 0; tt < 4; ++tt) {
      #pragma unroll
      for (int e = 0; e < 4; ++e) {
        int f_loc = fg * 16 + q * 4 + e;      // C: row = quad*4+reg
        int t_loc = tt * 16 + m;              // C: col = lane&15
        float r = accr[tt][e], im = acci[tt][e];
        float val;
        if (pl == 0) {
          val = sqrtf(fmaxf(r * r + im * im, EPSF));
        } else {
          bool risk = (r < TAU) && (fabsf(im) < TAU);
          val = risk ? SENTINEL : atan2f(im + EPSF, r + EPSF);
        }
        OB[f_loc * OBLD + t_loc] = val;
      }
    }
    __syncthreads();
    const long pb = ob + (pl ? plane : 0);
    for (int it = 0; it < 16; ++it) {         // 64 f-rows x 64 t, full lines
      int idx = it * 256 + tid;
      int f = fBase + (idx >> 6);
      int t = t0 + (idx & 63);
      if (f <= 256 && t < NT)
        out[pb + (long)f * NT + t] = OB[(idx >> 6) * OBLD + (idx & 63)];
    }
    __syncthreads();
  }
}

// Scan phase plane; recompute sentinel bins with fp32 SEQUENTIAL-k fmaf —
// the exact arithmetic of the 4/4-passing direct-conv kernels (correlates
// with the np reference's rounding near the atan2 cut; f64 does NOT).
__global__ __launch_bounds__(256)
void fixup_scan(const float* __restrict__ x, const float* __restrict__ w,
                float* __restrict__ out) {
  const long plane = (long)BATCH * NF * NT;
  float* ph = out + plane;
  const long stride = (long)gridDim.x * 256;
  for (long o = (long)blockIdx.x * 256 + threadIdx.x; o < plane; o += stride) {
    if (ph[o] == SENTINEL) {
      int bb = (int)(o / ((long)NF * NT));
      int rem = (int)(o - (long)bb * ((long)NF * NT));
      int f = rem / NT;
      int t = rem - f * NT;
      const float* xrow = x + (long)bb * NSAMP;
      const float* wr = w + (long)f * KLEN;
      const float* wi = w + (long)(NF + f) * KLEN;
      float r = 0.f, im = 0.f;
      const int k0 = t * INC - PADL;
      for (int k = 0; k < KLEN; ++k) {        // ascending k, single fp32 acc
        int g = k0 + k;
        float xv = (g >= 0 && g < NSAMP) ? xrow[g] : 0.0f;
        r = fmaf(wr[k], xv, r);
        im = fmaf(wi[k], xv, im);
      }
      out[o] = sqrtf(fmaxf(r * r + im * im, EPSF));
      ph[o] = atan2f(im + EPSF, r + EPSF);
    }
  }
}

extern "C" void kernel_launch(void* const* d_in, const int* in_sizes, int n_in,
                              void* d_out, int out_size, void* d_ws, size_t ws_size,
                              hipStream_t stream) {
  const float* x = (const float*)d_in[0];   // (16, 160000) fp32
  const float* w = (const float*)d_in[1];   // (514, 1, 400) fp32
  float* out = (float*)d_out;

  const size_t ws_needed = (size_t)2 * WROWS * KP * sizeof(short) + 64;  // ~856KB
  const int use_pre = (ws_size >= ws_needed) ? 1 : 0;
  short* WHg = (short*)d_ws;
  short* WLg = WHg + (size_t)WROWS * KP;

  if (use_pre) {
    int nblk = (WROWS * KP + 255) / 256;
    presplit_w<<<dim3(nblk), dim3(256), 0, stream>>>(w, WHg, WLg);
  }

  dim3 grid((NT + TTB - 1) / TTB, (NF + NFB - 1) / NFB, BATCH);  // 26 x 5 x 16
  convstft_mfma<<<grid, dim3(256), 0, stream>>>(x, w, out, WHg, WLg, use_pre);
  fixup_scan<<<dim3(2048), dim3(256), 0, stream>>>(x, w, out);
}